// Round 9
// baseline (425.131 us; speedup 1.0000x reference)
//
#include <hip/hip_runtime.h>

#define NPTS 100000
#define PB 64                         // points per block
#define NBLK ((NPTS + PB - 1) / PB)   // 1563
#define INF 1280

using short8 = __attribute__((ext_vector_type(8))) short;
using f32x4  = __attribute__((ext_vector_type(4))) float;

__device__ __forceinline__ unsigned short f2bf(float x) {
  unsigned u = __float_as_uint(x);
  return (unsigned short)((u + 0x7FFFu + ((u >> 16) & 1u)) >> 16);  // RNE
}
__device__ __forceinline__ unsigned pack2(float a, float b) {
  return (unsigned)f2bf(a) | ((unsigned)f2bf(b) << 16);
}
// 512B row + 16B-slot XOR swizzle: bijective per row; makes the gemm a-read
// (row=c16 varies across lanes, slot fixed) hit 16 distinct slots/quarter.
__device__ __forceinline__ unsigned char* swzp(unsigned char* base, int row, int inrow) {
  return base + row * 512 + ((inrow & ~15) ^ ((row & 15) << 4)) + (inrow & 15);
}

// ---- prep: in_f f32 -> bf16 (12.8 MB, L3-resident for gathers) ----
__global__ void k_prep(const float* __restrict__ in_f, unsigned short* __restrict__ inbf) {
  int i = blockIdx.x * 256 + threadIdx.x;
  if (i < 1600000) {
    float4 v = ((const float4*)in_f)[i];
    ushort4 o;
    o.x = f2bf(v.x); o.y = f2bf(v.y); o.z = f2bf(v.z); o.w = f2bf(v.w);
    ((ushort4*)inbf)[i] = o;
  }
}

// ---- retile linear_weights -> bf16 B-fragment order (R2-verified) ----
__global__ void k_wconv(const float* __restrict__ W, unsigned short* __restrict__ Wb) {
  int g = blockIdx.x * 256 + threadIdx.x;   // 0..327679
  int j = g & 7;
  int col = (g >> 3) & 15;
  int ks = (g >> 7) & 31;
  int rest = g >> 12;
  int ct = rest % 5, nt = rest / 5;
  int kh = ks * 8 + j;
  int m = kh >> 4, ci = kh & 15;
  Wb[g] = f2bf(W[(nt * 16 + col) * INF + (ct * 16 + ci) * 16 + m]);
}

// ---- fused: R5 structure + swizzled 512B LDS + b64 staging ----
// sF[p][x16][k16] bf16 swizzled; sA[p][k^256] A-frag order swizzled.
// Staging unit: thread -> (p = t>>3, h = (t>>2)&1, kq = t&3).
__global__ __launch_bounds__(512, 4) void k_fused(
    const unsigned short* __restrict__ inbf, const int* __restrict__ nbr,
    const float* __restrict__ wn_g, const float* __restrict__ add_f,
    const unsigned short* __restrict__ Wb, const float* __restrict__ bias,
    float* __restrict__ out)
{
  __shared__ __align__(16) unsigned char sF[PB * 512];  // 32768 B
  __shared__ __align__(16) unsigned char sA[PB * 512];  // 32768 B

  const int t = threadIdx.x;
  const int w = t >> 6, lane = t & 63;
  const int g16 = lane >> 4, c16 = lane & 15;
  const long p0 = (long)blockIdx.x * PB;

  // staging unit
  const int up = t >> 3, uh = (t >> 2) & 1, ukq = t & 3;
  long upp = p0 + up; if (upp >= NPTS) upp = NPTS - 1;
  const int4 uidx = *(const int4*)&nbr[upp * 16 + ukq * 4];

  unsigned gg[4][4];   // 4 gathered 16B granules (raw, packed late)
  unsigned pk[8][2];   // packed store values: pk[x] = k-quad of channel x

  auto gload = [&](int ct) {
#pragma unroll
    for (int j = 0; j < 4; ++j) {
      int idx = ((const int*)&uidx)[j];
      *(uint4*)&gg[j][0] = *(const uint4*)(inbf + (long)idx * 64 + ct * 16 + uh * 8);
    }
  };
  auto packg = [&]() {                 // R8-verified perm pack
#pragma unroll
    for (int x = 0; x < 8; ++x) {
      int wi = x >> 1;
      unsigned sel = (x & 1) ? 0x07060302u : 0x05040100u;
      pk[x][0] = __builtin_amdgcn_perm(gg[1][wi], gg[0][wi], sel);
      pk[x][1] = __builtin_amdgcn_perm(gg[3][wi], gg[2][wi], sel);
    }
  };
  auto floadpack = [&](const float* __restrict__ src) {  // src[(pp*16+k)*16+m]
    float4 av[4], bv[4];
#pragma unroll
    for (int j = 0; j < 4; ++j) {
      const float* s = src + (upp * 16 + ukq * 4 + j) * 16 + uh * 8;
      av[j] = *(const float4*)s;
      bv[j] = *(const float4*)(s + 4);
    }
#pragma unroll
    for (int x = 0; x < 8; ++x) {
      int e = x & 3;
      float e0 = (x < 4) ? ((const float*)&av[0])[e] : ((const float*)&bv[0])[e];
      float e1 = (x < 4) ? ((const float*)&av[1])[e] : ((const float*)&bv[1])[e];
      float e2 = (x < 4) ? ((const float*)&av[2])[e] : ((const float*)&bv[2])[e];
      float e3 = (x < 4) ? ((const float*)&av[3])[e] : ((const float*)&bv[3])[e];
      pk[x][0] = pack2(e0, e1);
      pk[x][1] = pack2(e2, e3);
    }
  };
  auto swrite = [&]() {                // 8 x ds_write_b64, <=2-way banks
#pragma unroll
    for (int x = 0; x < 8; ++x)
      *(uint2*)swzp(sF, up, (uh * 8 + x) * 32 + ukq * 8) = make_uint2(pk[x][0], pk[x][1]);
  };

  // ---- prologue ----
  gload(0);                            // issue gathers early (T14)
  floadpack(wn_g);
  swrite();                            // wn -> sF
  __syncthreads();

  short8 bfr[8];                       // wn B-frags for this wave's 8 points
#pragma unroll
  for (int i = 0; i < 8; ++i) {
    bfr[i] = (short8){0, 0, 0, 0, 0, 0, 0, 0};
    if (g16 < 2)
      bfr[i] = *(const short8*)swzp(sF, w * 8 + i, c16 * 32 + g16 * 16);
  }
  __syncthreads();                     // bfr reads done; sF reusable
  packg(); swrite();                   // feat(0) -> sF
  __syncthreads();

  auto pconv = [&]() {                 // per wave: 8 points, 1 MFMA each
#pragma unroll
    for (int g = 0; g < 2; ++g) {
      short8 af[4];
#pragma unroll
      for (int i = 0; i < 4; ++i) {
        af[i] = (short8){0, 0, 0, 0, 0, 0, 0, 0};
        if (g16 < 2)
          af[i] = *(const short8*)swzp(sF, w * 8 + g * 4 + i, c16 * 32 + g16 * 16);
      }
#pragma unroll
      for (int i = 0; i < 4; ++i) {
        int p = w * 8 + g * 4 + i;
        f32x4 d = __builtin_amdgcn_mfma_f32_16x16x32_bf16(
            af[i], bfr[g * 4 + i], (f32x4){0.f, 0.f, 0.f, 0.f}, 0, 0, 0);
        // D: row(c)=g16*4+r, col(m)=c16; k^=m*16+c -> inrow c16*32+g16*8+r*2
        *(uint2*)swzp(sA, p, c16 * 32 + g16 * 8) =
            make_uint2(pack2(d[0], d[1]), pack2(d[2], d[3]));
      }
    }
  };

  pconv();                             // ct=0
  __syncthreads();                     // sA(0) ready

  f32x4 acc[4][2];
#pragma unroll
  for (int rr = 0; rr < 4; ++rr)
#pragma unroll
    for (int ntl = 0; ntl < 2; ++ntl) acc[rr][ntl] = (f32x4){0.f, 0.f, 0.f, 0.f};

  auto gemm = [&](int ct) {            // wave: 4 row-tiles x 2 col-tiles (R5)
#pragma unroll
    for (int kl = 0; kl < 8; ++kl) {
      short8 a[4];
#pragma unroll
      for (int rr = 0; rr < 4; ++rr)
        a[rr] = *(const short8*)swzp(sA, rr * 16 + c16, kl * 64 + g16 * 16);
#pragma unroll
      for (int ntl = 0; ntl < 2; ++ntl) {
        int nt = w * 2 + ntl;
        short8 b = *(const short8*)(Wb + ((long)((nt * 5 + ct) * 32 + kl * 4 + g16) * 16 + c16) * 8);
#pragma unroll
        for (int rr = 0; rr < 4; ++rr)
          acc[rr][ntl] = __builtin_amdgcn_mfma_f32_16x16x32_bf16(a[rr], b, acc[rr][ntl], 0, 0, 0);
      }
    }
  };

  // ---- main loop (R5-proven schedule) ----
  for (int ct = 0; ct < 5; ++ct) {
    if (ct < 3) gload(ct + 1);         // issue-early
    else if (ct == 3) floadpack(add_f);
    gemm(ct);
    if (ct < 4) {
      if (ct < 3) packg();
      swrite();                        // write-late
      __syncthreads();                 // sF(ct+1) ready, sA consumed
      pconv();
      __syncthreads();                 // sA(ct+1) ready
    }
  }

  // ---- epilogue: both 64B halves of each 128B line back-to-back ----
  float bv0 = bias[(w * 2 + 0) * 16 + c16];
  float bv1 = bias[(w * 2 + 1) * 16 + c16];
#pragma unroll
  for (int rr = 0; rr < 4; ++rr) {
#pragma unroll
    for (int r = 0; r < 4; ++r) {
      long prow = p0 + rr * 16 + g16 * 4 + r;
      if (prow < NPTS) {
        float* o = out + prow * 256 + c16;
        o[(w * 2 + 0) * 16] = acc[rr][0][r] + bv0;
        o[(w * 2 + 1) * 16] = acc[rr][1][r] + bv1;
      }
    }
  }
}

extern "C" void kernel_launch(void* const* d_in, const int* in_sizes, int n_in,
                              void* d_out, int out_size, void* d_ws, size_t ws_size,
                              hipStream_t stream) {
  const float* in_f  = (const float*)d_in[0];
  const int*   nbr   = (const int*)d_in[1];
  const float* wn    = (const float*)d_in[5];
  const float* add_f = (const float*)d_in[6];
  const float* W     = (const float*)d_in[7];
  const float* bias  = (const float*)d_in[8];
  float* out = (float*)d_out;

  unsigned short* inbf = (unsigned short*)d_ws;                       // 12.8 MB
  unsigned short* Wb   = (unsigned short*)((char*)d_ws + 13631488);   // 640 KB

  k_prep<<<dim3(6250), dim3(256), 0, stream>>>(in_f, inbf);
  k_wconv<<<dim3(1280), dim3(256), 0, stream>>>(W, Wb);
  k_fused<<<dim3(NBLK), dim3(512), 0, stream>>>(inbf, nbr, wn, add_f, Wb, bias, out);
}

// Round 10
// 423.521 us; speedup vs baseline: 1.0038x; 1.0038x over previous
//
#include <hip/hip_runtime.h>

#define NPTS 100000
#define PB 64                         // points per block
#define NBLK ((NPTS + PB - 1) / PB)   // 1563
#define INF 1280

using short8 = __attribute__((ext_vector_type(8))) short;
using f32x4  = __attribute__((ext_vector_type(4))) float;

__device__ __forceinline__ unsigned short f2bf(float x) {
  unsigned u = __float_as_uint(x);
  return (unsigned short)((u + 0x7FFFu + ((u >> 16) & 1u)) >> 16);  // RNE
}
__device__ __forceinline__ unsigned pack2(float a, float b) {
  return (unsigned)f2bf(a) | ((unsigned)f2bf(b) << 16);
}
// 512B row + 16B-slot XOR swizzle: bijective per row; makes the gemm a-read
// (row=c16 varies across lanes, slot fixed) hit 16 distinct slots/quarter.
__device__ __forceinline__ unsigned char* swzp(unsigned char* base, int row, int inrow) {
  return base + row * 512 + ((inrow & ~15) ^ ((row & 15) << 4)) + (inrow & 15);
}

// ---- prep: in_f f32 -> bf16 (12.8 MB, L3-resident for gathers) ----
__global__ void k_prep(const float* __restrict__ in_f, unsigned short* __restrict__ inbf) {
  int i = blockIdx.x * 256 + threadIdx.x;
  if (i < 1600000) {
    float4 v = ((const float4*)in_f)[i];
    ushort4 o;
    o.x = f2bf(v.x); o.y = f2bf(v.y); o.z = f2bf(v.z); o.w = f2bf(v.w);
    ((ushort4*)inbf)[i] = o;
  }
}

// ---- retile linear_weights -> bf16 B-fragment order (R2-verified) ----
__global__ void k_wconv(const float* __restrict__ W, unsigned short* __restrict__ Wb) {
  int g = blockIdx.x * 256 + threadIdx.x;   // 0..327679
  int j = g & 7;
  int col = (g >> 3) & 15;
  int ks = (g >> 7) & 31;
  int rest = g >> 12;
  int ct = rest % 5, nt = rest / 5;
  int kh = ks * 8 + j;
  int m = kh >> 4, ci = kh & 15;
  Wb[g] = f2bf(W[(nt * 16 + col) * INF + (ct * 16 + ci) * 16 + m]);
}

// ---- fused: R9 structure, occupancy PINNED at 4 waves/EU ----
// amdgpu_waves_per_eu(4,4): without the upper pin the allocator targets 8
// waves/EU (64 VGPR) and spills ~50 regs/thread to scratch (R9: FETCH 831MB).
__global__ __launch_bounds__(512)
__attribute__((amdgpu_waves_per_eu(4, 4)))
void k_fused(
    const unsigned short* __restrict__ inbf, const int* __restrict__ nbr,
    const float* __restrict__ wn_g, const float* __restrict__ add_f,
    const unsigned short* __restrict__ Wb, const float* __restrict__ bias,
    float* __restrict__ out)
{
  __shared__ __align__(16) unsigned char sF[PB * 512];  // 32768 B
  __shared__ __align__(16) unsigned char sA[PB * 512];  // 32768 B

  const int t = threadIdx.x;
  const int w = t >> 6, lane = t & 63;
  const int g16 = lane >> 4, c16 = lane & 15;
  const long p0 = (long)blockIdx.x * PB;

  // staging unit
  const int up = t >> 3, uh = (t >> 2) & 1, ukq = t & 3;
  long upp = p0 + up; if (upp >= NPTS) upp = NPTS - 1;
  const int4 uidx = *(const int4*)&nbr[upp * 16 + ukq * 4];

  unsigned gg[4][4];   // 4 gathered 16B granules (raw, packed late)
  unsigned pk[8][2];   // packed store values: pk[x] = k-quad of channel x

  auto gload = [&](int ct) {
#pragma unroll
    for (int j = 0; j < 4; ++j) {
      int idx = ((const int*)&uidx)[j];
      *(uint4*)&gg[j][0] = *(const uint4*)(inbf + (long)idx * 64 + ct * 16 + uh * 8);
    }
  };
  auto packg = [&]() {                 // R8-verified perm pack
#pragma unroll
    for (int x = 0; x < 8; ++x) {
      int wi = x >> 1;
      unsigned sel = (x & 1) ? 0x07060302u : 0x05040100u;
      pk[x][0] = __builtin_amdgcn_perm(gg[1][wi], gg[0][wi], sel);
      pk[x][1] = __builtin_amdgcn_perm(gg[3][wi], gg[2][wi], sel);
    }
  };
  auto floadpack = [&](const float* __restrict__ src) {  // src[(pp*16+k)*16+m]
    float4 av[4], bv[4];
#pragma unroll
    for (int j = 0; j < 4; ++j) {
      const float* s = src + (upp * 16 + ukq * 4 + j) * 16 + uh * 8;
      av[j] = *(const float4*)s;
      bv[j] = *(const float4*)(s + 4);
    }
#pragma unroll
    for (int x = 0; x < 8; ++x) {
      int e = x & 3;
      float e0 = (x < 4) ? ((const float*)&av[0])[e] : ((const float*)&bv[0])[e];
      float e1 = (x < 4) ? ((const float*)&av[1])[e] : ((const float*)&bv[1])[e];
      float e2 = (x < 4) ? ((const float*)&av[2])[e] : ((const float*)&bv[2])[e];
      float e3 = (x < 4) ? ((const float*)&av[3])[e] : ((const float*)&bv[3])[e];
      pk[x][0] = pack2(e0, e1);
      pk[x][1] = pack2(e2, e3);
    }
  };
  auto swrite = [&]() {                // 8 x ds_write_b64, <=2-way banks
#pragma unroll
    for (int x = 0; x < 8; ++x)
      *(uint2*)swzp(sF, up, (uh * 8 + x) * 32 + ukq * 8) = make_uint2(pk[x][0], pk[x][1]);
  };

  // ---- prologue ----
  gload(0);                            // issue gathers early (T14)
  floadpack(wn_g);
  swrite();                            // wn -> sF
  __syncthreads();

  short8 bfr[8];                       // wn B-frags for this wave's 8 points
#pragma unroll
  for (int i = 0; i < 8; ++i) {
    bfr[i] = (short8){0, 0, 0, 0, 0, 0, 0, 0};
    if (g16 < 2)
      bfr[i] = *(const short8*)swzp(sF, w * 8 + i, c16 * 32 + g16 * 16);
  }
  __syncthreads();                     // bfr reads done; sF reusable
  packg(); swrite();                   // feat(0) -> sF
  __syncthreads();

  auto pconv = [&]() {                 // per wave: 8 points, 1 MFMA each
#pragma unroll
    for (int g = 0; g < 2; ++g) {
      short8 af[4];
#pragma unroll
      for (int i = 0; i < 4; ++i) {
        af[i] = (short8){0, 0, 0, 0, 0, 0, 0, 0};
        if (g16 < 2)
          af[i] = *(const short8*)swzp(sF, w * 8 + g * 4 + i, c16 * 32 + g16 * 16);
      }
#pragma unroll
      for (int i = 0; i < 4; ++i) {
        int p = w * 8 + g * 4 + i;
        f32x4 d = __builtin_amdgcn_mfma_f32_16x16x32_bf16(
            af[i], bfr[g * 4 + i], (f32x4){0.f, 0.f, 0.f, 0.f}, 0, 0, 0);
        // D: row(c)=g16*4+r, col(m)=c16; k^=m*16+c -> inrow c16*32+g16*8+r*2
        *(uint2*)swzp(sA, p, c16 * 32 + g16 * 8) =
            make_uint2(pack2(d[0], d[1]), pack2(d[2], d[3]));
      }
    }
  };

  pconv();                             // ct=0
  __syncthreads();                     // sA(0) ready

  f32x4 acc[4][2];
#pragma unroll
  for (int rr = 0; rr < 4; ++rr)
#pragma unroll
    for (int ntl = 0; ntl < 2; ++ntl) acc[rr][ntl] = (f32x4){0.f, 0.f, 0.f, 0.f};

  auto gemm = [&](int ct) {            // wave: 4 row-tiles x 2 col-tiles (R5)
#pragma unroll
    for (int kl = 0; kl < 8; ++kl) {
      short8 a[4];
#pragma unroll
      for (int rr = 0; rr < 4; ++rr)
        a[rr] = *(const short8*)swzp(sA, rr * 16 + c16, kl * 64 + g16 * 16);
#pragma unroll
      for (int ntl = 0; ntl < 2; ++ntl) {
        int nt = w * 2 + ntl;
        short8 b = *(const short8*)(Wb + ((long)((nt * 5 + ct) * 32 + kl * 4 + g16) * 16 + c16) * 8);
#pragma unroll
        for (int rr = 0; rr < 4; ++rr)
          acc[rr][ntl] = __builtin_amdgcn_mfma_f32_16x16x32_bf16(a[rr], b, acc[rr][ntl], 0, 0, 0);
      }
    }
  };

  // ---- main loop (R5-proven schedule) ----
  for (int ct = 0; ct < 5; ++ct) {
    if (ct < 3) gload(ct + 1);         // issue-early
    else if (ct == 3) floadpack(add_f);
    gemm(ct);
    if (ct < 4) {
      if (ct < 3) packg();
      swrite();                        // write-late
      __syncthreads();                 // sF(ct+1) ready, sA consumed
      pconv();
      __syncthreads();                 // sA(ct+1) ready
    }
  }

  // ---- epilogue: both 64B halves of each 128B line back-to-back ----
  float bv0 = bias[(w * 2 + 0) * 16 + c16];
  float bv1 = bias[(w * 2 + 1) * 16 + c16];
#pragma unroll
  for (int rr = 0; rr < 4; ++rr) {
#pragma unroll
    for (int r = 0; r < 4; ++r) {
      long prow = p0 + rr * 16 + g16 * 4 + r;
      if (prow < NPTS) {
        float* o = out + prow * 256 + c16;
        o[(w * 2 + 0) * 16] = acc[rr][0][r] + bv0;
        o[(w * 2 + 1) * 16] = acc[rr][1][r] + bv1;
      }
    }
  }
}

extern "C" void kernel_launch(void* const* d_in, const int* in_sizes, int n_in,
                              void* d_out, int out_size, void* d_ws, size_t ws_size,
                              hipStream_t stream) {
  const float* in_f  = (const float*)d_in[0];
  const int*   nbr   = (const int*)d_in[1];
  const float* wn    = (const float*)d_in[5];
  const float* add_f = (const float*)d_in[6];
  const float* W     = (const float*)d_in[7];
  const float* bias  = (const float*)d_in[8];
  float* out = (float*)d_out;

  unsigned short* inbf = (unsigned short*)d_ws;                       // 12.8 MB
  unsigned short* Wb   = (unsigned short*)((char*)d_ws + 13631488);   // 640 KB

  k_prep<<<dim3(6250), dim3(256), 0, stream>>>(in_f, inbf);
  k_wconv<<<dim3(1280), dim3(256), 0, stream>>>(W, Wb);
  k_fused<<<dim3(NBLK), dim3(512), 0, stream>>>(inbf, nbr, wn, add_f, Wb, bias, out);
}